// Round 8
// baseline (180.741 us; speedup 1.0000x reference)
//
#include <hip/hip_runtime.h>
#include <stdint.h>
#include <string.h>

#define BB 8
#define NN 4096
#define DD 256
#define SCALE 0.0625f
#define XS2 264   // xtile stride (bf16): 16B-aligned, 2-way-bank-free

using frag_ab = __attribute__((ext_vector_type(8))) short;   // 8 bf16
using frag_cd = __attribute__((ext_vector_type(4))) float;   // 4 fp32

__device__ __forceinline__ unsigned short f2bf(float f) {
    union { float f; unsigned u; } a; a.f = f;
    unsigned r = a.u + 0x7FFFu + ((a.u >> 16) & 1u);
    return (unsigned short)(r >> 16);
}
__device__ __forceinline__ float bf2f(unsigned short h) {
    union { unsigned u; float f; } a; a.u = ((unsigned)h) << 16;
    return a.f;
}

// ---- K1 setup (385 blocks):
// bx<128: P12t row (on-the-fly agent proj) + c2 for stage2 cols
// bx in [128,384): W3b row i = bf16((W_v@W_fc1@W_fc2)[i]); bx==384: b3
__global__ __launch_bounds__(256) void k_setup(
    const float* __restrict__ agent, const float* __restrict__ Wag,
    const float* __restrict__ bag, const float* __restrict__ Wqkv,
    const float* __restrict__ bqkv, const float* __restrict__ Wfc1,
    const float* __restrict__ bfc1, const float* __restrict__ Wfc2,
    unsigned short* __restrict__ P12t, float* __restrict__ c2,
    unsigned short* __restrict__ W3b, float* __restrict__ b3)
{
    __shared__ float arow[256];
    __shared__ float red[256];
    const int bx = blockIdx.x, tid = threadIdx.x;
    if (bx < 128) {
        const int c = bx;
        const int woff = (c < 64) ? 256 : 0;   // W_k for stage1, W_q for stage2
        const int aoff = (c < 64) ? 0 : 256;   // q_agent / k_agent
        const int row = c & 63;
        float s = bag[aoff + tid];
        for (int o = 0; o < 256; ++o) s += agent[row * 256 + o] * Wag[o * 512 + aoff + tid];
        arow[tid] = s;
        __syncthreads();
        float p = 0.f;
        const float* wr = &Wqkv[tid * 768 + woff];
#pragma unroll 8
        for (int o4 = 0; o4 < 64; ++o4) {
            float4 wv = *(const float4*)&wr[o4 * 4];
            float4 av = *(const float4*)&arow[o4 * 4];
            p += wv.x * av.x + wv.y * av.y + wv.z * av.z + wv.w * av.w;
        }
        P12t[(size_t)c * 256 + tid] = f2bf(SCALE * p);
        if (c >= 64) {
            red[tid] = bqkv[woff + tid] * arow[tid];
            __syncthreads();
            for (int st = 128; st; st >>= 1) {
                if (tid < st) red[tid] += red[tid + st];
                __syncthreads();
            }
            if (tid == 0) c2[c - 64] = SCALE * red[0];
        }
    } else if (bx < 384) {
        const int i = bx - 128;
        float t = 0.f;
        for (int o = 0; o < 256; ++o) t += Wqkv[i * 768 + 512 + o] * Wfc1[o * 256 + tid];
        arow[tid] = t;
        __syncthreads();
        float p = 0.f;
        for (int k = 0; k < 256; ++k) p += arow[k] * Wfc2[k * 256 + tid];
        W3b[(size_t)i * 256 + tid] = f2bf(p);
    } else {
        float t = bfc1[tid];
        for (int o = 0; o < 256; ++o) t += bqkv[512 + o] * Wfc1[o * 256 + tid];
        arow[tid] = t;
        __syncthreads();
        float p = 0.f;
        for (int k = 0; k < 256; ++k) p += arow[k] * Wfc2[k * 256 + tid];
        b3[tid] = p;
    }
}

// ---- K2: x-convert/transpose + logits MFMA; B-frags DIRECT FROM GLOBAL ----
// 32-tok tiles. waves: rt=w&1 rowtile, cg=w>>1 colgroup (cg0: stage1, cg1: stage2).
__global__ __launch_bounds__(256) void k_xlogits(
    const float* __restrict__ x, const unsigned short* __restrict__ P12t,
    const float* __restrict__ c2, unsigned short* __restrict__ xt,
    unsigned short* __restrict__ p1, unsigned short* __restrict__ p2b,
    float* __restrict__ statS)
{
    __shared__ unsigned short xtile[32 * XS2];
    __shared__ float Ss[2][64];
    const int chunk = blockIdx.x, b = blockIdx.y;
    const int n0 = chunk * 32;
    const int tid = threadIdx.x;
    const int w = tid >> 6, lane = tid & 63;
    const int ml = lane & 15, q = lane >> 4;
    const int rt = w & 1, cg = w >> 1;

    // Phase A: x fp32 -> xtile bf16
#pragma unroll
    for (int p = 0; p < 8; ++p) {
        int idx = p * 256 + tid;
        int tok = idx >> 6, d = (idx & 63) * 4;
        float4 v = *(const float4*)&x[(size_t)(b * 4096 + n0 + tok) * 256 + d];
        unsigned short u[4] = {f2bf(v.x), f2bf(v.y), f2bf(v.z), f2bf(v.w)};
        uint2 pk; memcpy(&pk, u, 8);
        *(uint2*)&xtile[tok * XS2 + d] = pk;
    }
    __syncthreads();
    // Phase A2: xt stores (drain overlaps MFMA below — no barrier until end)
#pragma unroll
    for (int p = 0; p < 8; ++p) {
        int idx = p * 256 + tid;
        int d = idx >> 3, seg = idx & 7;
        unsigned short u[4];
#pragma unroll
        for (int k = 0; k < 4; ++k) u[k] = xtile[(seg * 4 + k) * XS2 + d];
        uint2 pk; memcpy(&pk, u, 8);
        *(uint2*)&xt[(size_t)(b * 256 + d) * 4096 + n0 + seg * 4] = pk;
    }

    // Phase B: logits = xtile @ P12t^T, B-frags straight from global (L2)
    frag_cd acc[4];
#pragma unroll
    for (int j = 0; j < 4; ++j)
#pragma unroll
        for (int r = 0; r < 4; ++r) acc[j][r] = 0.f;

#pragma unroll
    for (int kb = 0; kb < 4; ++kb) {
#pragma unroll
        for (int ks = 0; ks < 2; ++ks) {
            const int kk = kb * 64 + ks * 32 + q * 8;
            frag_ab a = *(const frag_ab*)&xtile[(rt * 16 + ml) * XS2 + kk];
#pragma unroll
            for (int j = 0; j < 4; ++j) {
                frag_ab bf = *(const frag_ab*)&P12t[(size_t)(cg * 64 + j * 16 + ml) * 256 + kk];
                acc[j] = __builtin_amdgcn_mfma_f32_16x16x32_bf16(a, bf, acc[j], 0, 0, 0);
            }
        }
    }

    if (cg == 0) {
        // stage1: p1 = exp(l) bf16 (no max: logits ~N(0,1)); per-chunk sums
#pragma unroll
        for (int j = 0; j < 4; ++j) {
            const int ag = j * 16 + ml;
            float e[4];
#pragma unroll
            for (int r = 0; r < 4; ++r) e[r] = __expf(acc[j][r]);
            unsigned short u[4] = {f2bf(e[0]), f2bf(e[1]), f2bf(e[2]), f2bf(e[3])};
            uint2 pk; memcpy(&pk, u, 8);
            *(uint2*)&p1[(size_t)(b * 64 + ag) * 4096 + n0 + rt * 16 + q * 4] = pk;
            float s = e[0] + e[1] + e[2] + e[3];
            s += __shfl_xor(s, 16);
            s += __shfl_xor(s, 32);
            if (q == 0) Ss[rt][ag] = s;
        }
    } else {
        // stage2: softmax over 64 agents per token
        float cc[4];
#pragma unroll
        for (int j = 0; j < 4; ++j) cc[j] = c2[j * 16 + ml];
#pragma unroll
        for (int r = 0; r < 4; ++r) {
            float e[4], s = 0.f;
#pragma unroll
            for (int j = 0; j < 4; ++j) {
                e[j] = __expf(acc[j][r] + cc[j]);
                s += e[j];
            }
#pragma unroll
            for (int mask = 1; mask <= 8; mask <<= 1) s += __shfl_xor(s, mask);
            float inv = 1.f / s;
            const int tok = n0 + rt * 16 + q * 4 + r;
#pragma unroll
            for (int j = 0; j < 4; ++j)
                p2b[(size_t)(b * 4096 + tok) * 64 + j * 16 + ml] = f2bf(e[j] * inv);
        }
    }
    __syncthreads();
    if (tid < 64)
        statS[(size_t)(b * 64 + tid) * 128 + chunk] = Ss[0][tid] + Ss[1][tid];
}

// ---- K3: normalize p1 + P @ xt partials; B(xt)-frags DIRECT FROM GLOBAL ----
__global__ __launch_bounds__(256) void k_va(
    const unsigned short* __restrict__ p1, const float* __restrict__ statS,
    const unsigned short* __restrict__ xt, unsigned short* __restrict__ part)
{
    __shared__ unsigned short As[64 * 152];   // agents x 128 tok (P bf16)
    __shared__ float Rs[4][64], Inv[64];
    const int s = blockIdx.x, dh = blockIdx.y, b = blockIdx.z;
    const int tid = threadIdx.x;
    const int w = tid >> 6, lane = tid & 63;
    const int ml = lane & 15, q = lane >> 4;

    // row sums: 4-way split over 128 chunks
    {
        const int a = tid & 63, qq = tid >> 6;
        const float* ps = &statS[(size_t)(b * 64 + a) * 128 + qq * 32];
        float sum = 0.f;
#pragma unroll
        for (int p = 0; p < 8; ++p) {
            float4 s4 = *(const float4*)&ps[p * 4];
            sum += s4.x + s4.y + s4.z + s4.w;
        }
        Rs[qq][a] = sum;
    }
    __syncthreads();
    if (tid < 64)
        Inv[tid] = 1.f / (Rs[0][tid] + Rs[1][tid] + Rs[2][tid] + Rs[3][tid]);
    __syncthreads();
    // stage P = p1 * inv (bf16), 8-wide
#pragma unroll
    for (int p = 0; p < 4; ++p) {
        int idx8 = (p * 256 + tid) * 8;
        int ag = idx8 >> 7, t = idx8 & 127;
        uint4 pk = *(const uint4*)&p1[(size_t)(b * 64 + ag) * 4096 + s * 128 + t];
        unsigned short in[8]; memcpy(in, &pk, 16);
        float inv = Inv[ag];
        unsigned short u[8];
#pragma unroll
        for (int k = 0; k < 8; ++k) u[k] = f2bf(bf2f(in[k]) * inv);
        uint4 po; memcpy(&po, u, 16);
        *(uint4*)&As[ag * 152 + t] = po;
    }
    __syncthreads();

    frag_cd acc[4];
#pragma unroll
    for (int i = 0; i < 4; ++i)
#pragma unroll
        for (int r = 0; r < 4; ++r) acc[i][r] = 0.f;
#pragma unroll
    for (int ks = 0; ks < 4; ++ks) {
        const int kk = ks * 32 + q * 8;
        frag_ab bf = *(const frag_ab*)&xt[(size_t)(b * 256 + dh * 64 + w * 16 + ml) * 4096 +
                                          s * 128 + kk];
#pragma unroll
        for (int i = 0; i < 4; ++i) {
            frag_ab a = *(const frag_ab*)&As[(i * 16 + ml) * 152 + kk];
            acc[i] = __builtin_amdgcn_mfma_f32_16x16x32_bf16(a, bf, acc[i], 0, 0, 0);
        }
    }
    const int d = dh * 64 + w * 16 + ml;
#pragma unroll
    for (int i = 0; i < 4; ++i)
#pragma unroll
        for (int r = 0; r < 4; ++r)
            part[(size_t)((s * 8 + b) * 64 + i * 16 + q * 4 + r) * 256 + d] =
                f2bf(acc[i][r]);
}

// ---- K4: reduce 32 bf16 partials + @W3b + b3 -> va3t[b][d][ag] bf16 ----
__global__ __launch_bounds__(256) void k_fc(
    const unsigned short* __restrict__ part, const unsigned short* __restrict__ W3b,
    const float* __restrict__ b3, unsigned short* __restrict__ va3t)
{
    __shared__ float rowb[256];
    const int row = blockIdx.x, tid = threadIdx.x;
    const int b = row >> 6, agc = row & 63;
    float sv = 0.f;
    for (int s = 0; s < 32; ++s)
        sv += bf2f(part[(size_t)((s * 8 + b) * 64 + agc) * 256 + tid]);
    rowb[tid] = sv;
    __syncthreads();
    float s2 = b3[tid];
    for (int k = 0; k < 256; ++k) s2 += rowb[k] * bf2f(W3b[(size_t)k * 256 + tid]);
    va3t[(size_t)(b * 256 + tid) * 64 + agc] = f2bf(s2);
}

// ---- K5: stage2, ZERO LDS / ZERO BARRIERS: C[d][tok] = va3t @ p2b^T + bias + x ----
// 32-tok tiles (1024 blocks). x prefetched into registers before the MFMAs.
__global__ __launch_bounds__(256) void k_stage2(
    const unsigned short* __restrict__ p2b, const unsigned short* __restrict__ va3t,
    const float* __restrict__ x, const float* __restrict__ bfc2,
    float* __restrict__ out)
{
    const int n0 = blockIdx.x * 32, b = blockIdx.y;
    const int tid = threadIdx.x;
    const int w = tid >> 6, lane = tid & 63;
    const int ml = lane & 15, q = lane >> 4;

    // prefetch x (residual) — independent of everything, overlaps frag loads+MFMA
    float4 xr[4][2];
#pragma unroll
    for (int i = 0; i < 4; ++i)
#pragma unroll
        for (int j = 0; j < 2; ++j)
            xr[i][j] = *(const float4*)&x[(size_t)(b * 4096 + n0 + j * 16 + ml) * 256 +
                                          w * 64 + i * 16 + q * 4];

    // A-frags: va3t rows (d), B-frags: p2b rows (tok) — both k(=agent)-contiguous
    frag_ab a[4][2], bf[2][2];
#pragma unroll
    for (int ks = 0; ks < 2; ++ks) {
        const int kk = ks * 32 + q * 8;
#pragma unroll
        for (int i = 0; i < 4; ++i)
            a[i][ks] = *(const frag_ab*)&va3t[(size_t)(b * 256 + w * 64 + i * 16 + ml) * 64 + kk];
#pragma unroll
        for (int j = 0; j < 2; ++j)
            bf[j][ks] = *(const frag_ab*)&p2b[(size_t)(b * 4096 + n0 + j * 16 + ml) * 64 + kk];
    }

    frag_cd acc[4][2];
#pragma unroll
    for (int i = 0; i < 4; ++i)
#pragma unroll
        for (int j = 0; j < 2; ++j)
#pragma unroll
            for (int r = 0; r < 4; ++r) acc[i][j][r] = 0.f;
#pragma unroll
    for (int ks = 0; ks < 2; ++ks)
#pragma unroll
        for (int i = 0; i < 4; ++i)
#pragma unroll
            for (int j = 0; j < 2; ++j)
                acc[i][j] = __builtin_amdgcn_mfma_f32_16x16x32_bf16(
                    a[i][ks], bf[j][ks], acc[i][j], 0, 0, 0);

#pragma unroll
    for (int i = 0; i < 4; ++i) {
        const int d0 = w * 64 + i * 16 + q * 4;
        float4 bias = *(const float4*)&bfc2[d0];
#pragma unroll
        for (int j = 0; j < 2; ++j) {
            size_t ad = (size_t)(b * 4096 + n0 + j * 16 + ml) * 256 + d0;
            float4 o;
            o.x = acc[i][j][0] + bias.x + xr[i][j].x;
            o.y = acc[i][j][1] + bias.y + xr[i][j].y;
            o.z = acc[i][j][2] + bias.z + xr[i][j].z;
            o.w = acc[i][j][3] + bias.w + xr[i][j].w;
            *(float4*)&out[ad] = o;
        }
    }
}

extern "C" void kernel_launch(void* const* d_in, const int* in_sizes, int n_in,
                              void* d_out, int out_size, void* d_ws, size_t ws_size,
                              hipStream_t stream) {
    const float* agent = (const float*)d_in[0];
    const float* x     = (const float*)d_in[1];
    const float* Wqkv  = (const float*)d_in[2];
    const float* bqkv  = (const float*)d_in[3];
    const float* Wag   = (const float*)d_in[4];
    const float* bag   = (const float*)d_in[5];
    const float* Wfc1  = (const float*)d_in[6];
    const float* bfc1  = (const float*)d_in[7];
    const float* Wfc2  = (const float*)d_in[8];
    const float* bfc2  = (const float*)d_in[9];
    float* out = (float*)d_out;

    char* w = (char*)d_ws;
    size_t off = 0;
    unsigned short* xt   = (unsigned short*)(w + off); off += (size_t)BB * DD * NN * 2;   // 16.8 MB
    unsigned short* p1   = (unsigned short*)(w + off); off += (size_t)BB * 64 * NN * 2;   // 4.2 MB
    unsigned short* p2b  = (unsigned short*)(w + off); off += (size_t)BB * NN * 64 * 2;   // 4.2 MB
    unsigned short* part = (unsigned short*)(w + off); off += (size_t)32 * BB * 64 * 256 * 2; // 8.4 MB
    float* statS = (float*)(w + off); off += (size_t)BB * 64 * 128 * 4;                   // 256 KB
    unsigned short* P12t = (unsigned short*)(w + off); off += (size_t)128 * 256 * 2;
    float* c2   = (float*)(w + off); off += 256 * 4;
    unsigned short* W3b = (unsigned short*)(w + off); off += (size_t)256 * 256 * 2;
    float* b3   = (float*)(w + off); off += 256 * 4;
    unsigned short* va3t = (unsigned short*)(w + off); off += (size_t)BB * DD * 64 * 2;

    k_setup<<<385, 256, 0, stream>>>(agent, Wag, bag, Wqkv, bqkv, Wfc1, bfc1, Wfc2,
                                     P12t, c2, W3b, b3);
    k_xlogits<<<dim3(128, BB), 256, 0, stream>>>(x, P12t, c2, xt, p1, p2b, statS);
    k_va<<<dim3(32, 4, BB), 256, 0, stream>>>(p1, statS, xt, part);
    k_fc<<<512, 256, 0, stream>>>(part, W3b, b3, va3t);
    k_stage2<<<dim3(128, BB), 256, 0, stream>>>(p2b, va3t, x, bfc2, out);
}